// Round 13
// baseline (190.655 us; speedup 1.0000x reference)
//
#include <hip/hip_runtime.h>
#include <hip/hip_bf16.h>

constexpr int N_NODES = 100000;
constexpr int N_EDGES = 1600000;
constexpr int D = 128;
constexpr int N_CLASSES = 64;

constexpr int PART_NODES = 32;                 // nodes per partition
constexpr int NPART = N_NODES / PART_NODES;    // 3125 (exact)
constexpr int NB1 = 49;                        // coarse buckets (2048 nodes)
constexpr int CAP1 = 40960;                    // entries per coarse bucket
constexpr int SUBB = 10;                       // pass-B sub-blocks per bucket
constexpr int CHUNK = CAP1 / SUBB;             // 4096
constexpr int CAP2 = 1024;                     // per-partition slab (mean 512)
constexpr int NCTR2 = NB1 * 64;                // 3136 fine counters (3125 used)
constexpr int EB1 = (N_EDGES + 1023) / 1024;   // 1563 bin1 blocks
constexpr int CVTB = N_NODES * (D / 4) / 256;  // 12500 cvt blocks (exact)
constexpr int PKB = 36;                        // 144 weight tiles / 4 per block

typedef __attribute__((ext_vector_type(8))) short short8;
typedef __attribute__((ext_vector_type(4))) float f32x4;
typedef __attribute__((ext_vector_type(2))) float f32x2;

static __device__ __forceinline__ float bf2f(unsigned int lo16) {
    unsigned int x = lo16 << 16;
    return __builtin_bit_cast(float, x);
}
static __device__ __forceinline__ unsigned short f2bf(float f) {
    unsigned int x = __builtin_bit_cast(unsigned int, f);
    x += 0x7fffu + ((x >> 16) & 1u);          // RNE
    return (unsigned short)(x >> 16);
}
static __device__ __forceinline__ unsigned int pack4_fp8(float a, float b,
                                                         float c, float d) {
    int v = __builtin_amdgcn_cvt_pk_fp8_f32(a, b, 0, false);   // low word
    v = __builtin_amdgcn_cvt_pk_fp8_f32(c, d, v, true);        // high word
    return (unsigned int)v;
}
static __device__ __forceinline__ unsigned char f2fp8(float a) {
    return (unsigned char)(__builtin_amdgcn_cvt_pk_fp8_f32(a, a, 0, false) & 0xff);
}
static __device__ __forceinline__ void dec8(uint2 u, float* acc) {
    f32x2 q;
    q = __builtin_amdgcn_cvt_pk_f32_fp8(u.x, false); acc[0] += q[0]; acc[1] += q[1];
    q = __builtin_amdgcn_cvt_pk_f32_fp8(u.x, true);  acc[2] += q[0]; acc[3] += q[1];
    q = __builtin_amdgcn_cvt_pk_f32_fp8(u.y, false); acc[4] += q[0]; acc[5] += q[1];
    q = __builtin_amdgcn_cvt_pk_f32_fp8(u.y, true);  acc[6] += q[0]; acc[7] += q[1];
}

// ---------------------------------------------------------------------------
// 1) prep: [bin1: LDS sort by coarse bucket, RELATIVE cursors (pre-zeroed by
//    memset)] ∥ [feat fp32->bf16+fp8] ∥ [weight packing]
// ---------------------------------------------------------------------------
__global__ __launch_bounds__(256) void prep_k(const int* __restrict__ src,
                                              const int* __restrict__ dst,
                                              int* __restrict__ cursor1,
                                              unsigned int* __restrict__ pack1,
                                              const float* __restrict__ feat,
                                              unsigned short* __restrict__ fbuf,
                                              unsigned int* __restrict__ f8buf,
                                              const float* __restrict__ Ws1,
                                              const float* __restrict__ Wn1,
                                              const float* __restrict__ Ws2,
                                              const float* __restrict__ Wn2,
                                              const float* __restrict__ Wo,
                                              unsigned short* __restrict__ wp1,
                                              unsigned short* __restrict__ wp2,
                                              unsigned short* __restrict__ wpo) {
    __shared__ unsigned int lpay[1024];
    __shared__ unsigned char lcb[1024];
    __shared__ int hist[NB1], loff[NB1], gpos[NB1], lcur[NB1];

    const int b = blockIdx.x;
    const int t = threadIdx.x;

    if (b < EB1) {
        // ---- bin pass A (relative cursor: pos = cb*CAP1 + rel) ----
        const int ebase = b * 1024;
        int nblk = N_EDGES - ebase;
        if (nblk > 1024) nblk = 1024;
        const bool ok = (t * 4 < nblk);

        if (t < NB1) hist[t] = 0;
        __syncthreads();

        int4 d4, s4;
        if (ok) {
            d4 = *(const int4*)(dst + ebase + t * 4);
            s4 = *(const int4*)(src + ebase + t * 4);
            atomicAdd(&hist[d4.x >> 11], 1);
            atomicAdd(&hist[d4.y >> 11], 1);
            atomicAdd(&hist[d4.z >> 11], 1);
            atomicAdd(&hist[d4.w >> 11], 1);
        }
        __syncthreads();

        if (t == 0) {
            int run = 0;
            #pragma unroll
            for (int k = 0; k < NB1; ++k) { loff[k] = run; run += hist[k]; }
        }
        __syncthreads();
        if (t < NB1) {
            gpos[t] = atomicAdd(cursor1 + t, hist[t]);   // relative base
            lcur[t] = loff[t];
        }
        __syncthreads();

        if (ok) {
            #pragma unroll
            for (int k = 0; k < 4; ++k) {
                int dd = (k == 0) ? d4.x : (k == 1) ? d4.y : (k == 2) ? d4.z : d4.w;
                int ss = (k == 0) ? s4.x : (k == 1) ? s4.y : (k == 2) ? s4.z : s4.w;
                int cb = dd >> 11;
                int pos = atomicAdd(&lcur[cb], 1);
                lpay[pos] = ((unsigned int)(dd & 2047) << 17) | (unsigned int)ss;
                lcb[pos] = (unsigned char)cb;
            }
        }
        __syncthreads();

        for (int i = t; i < nblk; i += 256) {
            int cb = lcb[i];
            int rel = gpos[cb] + (i - loff[cb]);
            if (rel < CAP1) pack1[(size_t)cb * CAP1 + rel] = lpay[i];
        }
    } else if (b < EB1 + CVTB) {
        int i = (b - EB1) * 256 + t;           // float4 chunk id, 3.2M exact
        float4 v = ((const float4*)feat)[i];
        ushort4 r;
        r.x = f2bf(v.x); r.y = f2bf(v.y); r.z = f2bf(v.z); r.w = f2bf(v.w);
        ((ushort4*)fbuf)[i] = r;
        f8buf[i] = pack4_fp8(v.x, v.y, v.z, v.w);
    } else {
        int g = (b - EB1 - CVTB) * 4 + (t >> 6);   // weight tile 0..143
        if (g >= 144) return;
        int lane = t & 63;
        const float *Wa, *Wb;
        unsigned short* wp;
        int DOUT, bb;
        if (g < 64)       { Wa = Ws1; Wb = Wn1; wp = wp1; DOUT = 128; bb = g; }
        else if (g < 128) { Wa = Ws2; Wb = Wn2; wp = wp2; DOUT = 128; bb = g - 64; }
        else              { Wa = Wo;  Wb = nullptr; wp = wpo; DOUT = 64; bb = g - 128; }
        int NCT = DOUT / 16;
        int kstep = bb / NCT;
        int ct = bb % NCT;
        int col = ct * 16 + (lane & 15);
        int kbase = kstep * 32 + (lane >> 4) * 8;
        unsigned short r[8];
        #pragma unroll
        for (int j = 0; j < 8; ++j) {
            int k = kbase + j;
            float w = (k < 128) ? Wa[(size_t)k * DOUT + col]
                                : Wb[(size_t)(k - 128) * DOUT + col];
            r[j] = f2bf(w);
        }
        *(short8*)(wp + ((size_t)((kstep * NCT + ct) * 64 + lane)) * 8) =
            *(const short8*)r;
    }
}

// ---------------------------------------------------------------------------
// 2) pass B: sort each coarse-bucket chunk by partition (pw = pk>>22),
//    bulk-reserve RELATIVE, full-line run writes. payload2 = pk & 0x3fffff.
// ---------------------------------------------------------------------------
__global__ __launch_bounds__(256) void bin2_k(const int* __restrict__ cursor1,
                                              int* __restrict__ cursor2,
                                              const unsigned int* __restrict__ pack1,
                                              unsigned int* __restrict__ pack2) {
    __shared__ unsigned int lpay[CHUNK];       // 16 KB
    __shared__ unsigned int lsort[CHUNK];      // 16 KB
    __shared__ int hist[64], loff[64], gpos[64], lcur[64];

    const int t = threadIdx.x;
    const int cb = blockIdx.x / SUBB;
    const int sb = blockIdx.x % SUBB;

    int cnt = cursor1[cb];                     // relative count
    if (cnt > CAP1) cnt = CAP1;
    const int base = sb * CHUNK;
    int n = cnt - base;
    if (n <= 0) return;
    if (n > CHUNK) n = CHUNK;

    if (t < 64) hist[t] = 0;
    __syncthreads();

    const unsigned int* gsrc = pack1 + (size_t)cb * CAP1 + base;
    for (int i = t; i < n; i += 256) {
        unsigned int pk = gsrc[i];
        lpay[i] = pk;
        atomicAdd(&hist[pk >> 22], 1);
    }
    __syncthreads();

    if (t == 0) {
        int run = 0;
        #pragma unroll
        for (int k = 0; k < 64; ++k) { loff[k] = run; run += hist[k]; }
    }
    __syncthreads();
    if (t < 64) {
        gpos[t] = atomicAdd(cursor2 + cb * 64 + t, hist[t]);   // relative
        lcur[t] = loff[t];
    }
    __syncthreads();

    for (int i = t; i < n; i += 256) {
        unsigned int pk = lpay[i];
        int pos = atomicAdd(&lcur[pk >> 22], 1);
        lsort[pos] = pk;
    }
    __syncthreads();

    for (int i = t; i < n; i += 256) {
        unsigned int pk = lsort[i];
        int pw = pk >> 22;
        int p = cb * 64 + pw;
        int rel = gpos[pw] + (i - loff[pw]);
        if (rel < CAP2) pack2[((size_t)p << 10) + rel] = pk & 0x003fffffu;
    }
}

// ---------------------------------------------------------------------------
// 3) FUSED layer: one block per partition (32 nodes).
//    Stage slab + per-node counting sort; fp8 register gather 4-deep
//    (whole mean-degree node in flight at once); bf16 mean into LDS; MFMA.
//    !OUTPROJ: epilogue writes bf16 h AND its fp8 shadow.
//    OUTPROJ:  restage h in LDS, phase C MFMA out = h @ Wout + bout (fp32).
// ---------------------------------------------------------------------------
template <bool OUTPROJ>
__global__ __launch_bounds__(256) void fused_k(const unsigned short* __restrict__ xin,
                                               const unsigned char* __restrict__ x8,
                                               const unsigned int* __restrict__ pack,
                                               const int* __restrict__ cursor2,
                                               const short8* __restrict__ wp,
                                               const float* __restrict__ bias,
                                               unsigned short* __restrict__ xout,
                                               unsigned char* __restrict__ x8out,
                                               const short8* __restrict__ wpo,
                                               const float* __restrict__ bout,
                                               float* __restrict__ outp) {
    __shared__ unsigned int eraw[CAP2];
    __shared__ unsigned int ssrc[CAP2];
    __shared__ int nsh;
    __shared__ int bcnt[32];
    __shared__ int boff[33];
    __shared__ unsigned short mlds[PART_NODES][136];   // stride 272 B

    const int t = threadIdx.x;
    const int p = blockIdx.x;

    if (t == 0) {
        int c = cursor2[p];                    // relative count
        nsh = (c < CAP2) ? c : CAP2;
    }
    if (t < 32) bcnt[t] = 0;
    __syncthreads();
    const int n = nsh;

    // stage slab + per-node histogram
    const unsigned int* gsrc = pack + ((size_t)p << 10);
    for (int i = t; i < n; i += 256) {
        unsigned int pk = gsrc[i];
        eraw[i] = pk;
        atomicAdd(&bcnt[pk >> 17], 1);
    }
    __syncthreads();

    if (t == 0) {
        int s = 0;
        #pragma unroll
        for (int i = 0; i < 32; ++i) { boff[i] = s; s += bcnt[i]; }
        boff[32] = s;
    }
    __syncthreads();
    if (t < 32) bcnt[t] = boff[t];             // reuse as cursor
    __syncthreads();

    for (int i = t; i < n; i += 256) {
        unsigned int pk = eraw[i];
        int pos = atomicAdd(&bcnt[pk >> 17], 1);
        ssrc[pos] = pk & 0x1ffffu;
    }
    __syncthreads();

    // ---- phase A: fp8 gather into mlds (4-deep: 16 edge-loads in flight) ----
    const int w = t >> 6, lane = t & 63;
    const int sub = lane >> 4;                 // edge slot 0..3
    const int cl8 = (lane & 15) * 8;           // byte offset of column group
    const int cl = lane & 15;

    for (int g = 0; g < 8; ++g) {
        const int ni = w * 8 + g;
        const int b = boff[ni];
        const int eN = boff[ni + 1];

        float acc[8];
        #pragma unroll
        for (int r = 0; r < 8; ++r) acc[r] = 0.f;

        int i = b + sub;
        for (; i + 12 < eN; i += 16) {
            unsigned s0 = ssrc[i], s1 = ssrc[i + 4], s2 = ssrc[i + 8], s3 = ssrc[i + 12];
            uint2 u0 = *(const uint2*)(x8 + ((s0 << 7) + cl8));
            uint2 u1 = *(const uint2*)(x8 + ((s1 << 7) + cl8));
            uint2 u2 = *(const uint2*)(x8 + ((s2 << 7) + cl8));
            uint2 u3 = *(const uint2*)(x8 + ((s3 << 7) + cl8));
            dec8(u0, acc); dec8(u1, acc); dec8(u2, acc); dec8(u3, acc);
        }
        for (; i + 4 < eN; i += 8) {
            unsigned s0 = ssrc[i], s1 = ssrc[i + 4];
            uint2 u0 = *(const uint2*)(x8 + ((s0 << 7) + cl8));
            uint2 u1 = *(const uint2*)(x8 + ((s1 << 7) + cl8));
            dec8(u0, acc); dec8(u1, acc);
        }
        if (i < eN) {
            unsigned s0 = ssrc[i];
            uint2 u0 = *(const uint2*)(x8 + ((s0 << 7) + cl8));
            dec8(u0, acc);
        }
        #pragma unroll
        for (int r = 0; r < 8; ++r) {
            acc[r] += __shfl_xor(acc[r], 16);
            acc[r] += __shfl_xor(acc[r], 32);
        }
        float inv = 1.0f / fmaxf((float)(eN - b), 1.0f);
        float lo = acc[sub * 2 + 0] * inv;
        float hi = acc[sub * 2 + 1] * inv;
        unsigned int o = ((unsigned int)f2bf(hi) << 16) | (unsigned int)f2bf(lo);
        *(unsigned int*)(&mlds[ni][cl * 8 + sub * 2]) = o;
    }
    __syncthreads();

    // ---- phase B: 32-row GEMM, K=256 (self 0..127 global bf16, mean LDS) ----
    const int frag = w & 1;                    // 16-row fragment 0/1
    const int cg0 = (w >> 1) * 4;              // col-tile group base (of 8)
    const int r15 = lane & 15;
    const int khi = lane >> 4;                 // 0..3
    const int row0 = p * PART_NODES + frag * 16;
    const unsigned short* arow = xin + (size_t)(row0 + r15) * 128 + khi * 8;

    f32x4 acc[4];
    #pragma unroll
    for (int c = 0; c < 4; ++c) acc[c] = {0.f, 0.f, 0.f, 0.f};

    #pragma unroll
    for (int ks = 0; ks < 8; ++ks) {
        short8 a;
        if (ks < 4) a = *(const short8*)(arow + ks * 32);
        else        a = *(const short8*)(&mlds[frag * 16 + r15][(ks - 4) * 32 + khi * 8]);
        #pragma unroll
        for (int c = 0; c < 4; ++c) {
            short8 b = wp[(ks * 8 + cg0 + c) * 64 + lane];
            acc[c] = __builtin_amdgcn_mfma_f32_16x16x32_bf16(a, b, acc[c], 0, 0, 0);
        }
    }

    const int rhi = khi, col0 = r15;
    if (!OUTPROJ) {
        #pragma unroll
        for (int c = 0; c < 4; ++c) {
            float bv = bias[(cg0 + c) * 16 + col0];
            #pragma unroll
            for (int j = 0; j < 4; ++j) {
                float v = fmaxf(acc[c][j] + bv, 0.f);
                size_t off = (size_t)(row0 + rhi * 4 + j) * 128 + (cg0 + c) * 16 + col0;
                xout[off] = f2bf(v);
                x8out[off] = f2fp8(v);         // fp8 shadow for next layer
            }
        }
    } else {
        __syncthreads();                        // all mlds reads done
        // restage h tile (bias+relu) into mlds as bf16
        #pragma unroll
        for (int c = 0; c < 4; ++c) {
            float bv = bias[(cg0 + c) * 16 + col0];
            #pragma unroll
            for (int j = 0; j < 4; ++j) {
                float v = fmaxf(acc[c][j] + bv, 0.f);
                mlds[frag * 16 + rhi * 4 + j][(cg0 + c) * 16 + col0] = f2bf(v);
            }
        }
        __syncthreads();
        // ---- phase C: out[32 x 64] = h[32 x 128] @ Wout + bout ----
        const int frag2 = w & 1;
        const int ct0 = (w >> 1) * 2;          // 2 col-tiles of 4
        f32x4 oacc[2];
        oacc[0] = {0.f, 0.f, 0.f, 0.f};
        oacc[1] = {0.f, 0.f, 0.f, 0.f};
        #pragma unroll
        for (int ks = 0; ks < 4; ++ks) {
            short8 a = *(const short8*)(&mlds[frag2 * 16 + r15][ks * 32 + khi * 8]);
            #pragma unroll
            for (int c = 0; c < 2; ++c) {
                short8 b = wpo[(ks * 4 + ct0 + c) * 64 + lane];
                oacc[c] = __builtin_amdgcn_mfma_f32_16x16x32_bf16(a, b, oacc[c], 0, 0, 0);
            }
        }
        #pragma unroll
        for (int c = 0; c < 2; ++c) {
            float bv = bout[(ct0 + c) * 16 + col0];
            #pragma unroll
            for (int j = 0; j < 4; ++j) {
                outp[(size_t)(p * PART_NODES + frag2 * 16 + rhi * 4 + j) * N_CLASSES
                     + (ct0 + c) * 16 + col0] = oacc[c][j] + bv;
            }
        }
    }
}

// ---------------------------------------------------------------------------
extern "C" void kernel_launch(void* const* d_in, const int* in_sizes, int n_in,
                              void* d_out, int out_size, void* d_ws, size_t ws_size,
                              hipStream_t stream) {
    const float* feat   = (const float*)d_in[0];
    const int*   src    = (const int*)d_in[1];
    const int*   dst    = (const int*)d_in[2];
    const float* Wself1 = (const float*)d_in[3];
    const float* Wneigh1= (const float*)d_in[4];
    const float* b1     = (const float*)d_in[5];
    const float* Wself2 = (const float*)d_in[6];
    const float* Wneigh2= (const float*)d_in[7];
    const float* b2     = (const float*)d_in[8];
    const float* Wout   = (const float*)d_in[9];
    const float* bout   = (const float*)d_in[10];
    float* out = (float*)d_out;
    (void)ws_size;

    // workspace layout (~100 MB)
    int* cursor1 = (int*)d_ws;                                    // 49 (pad 64)
    int* cursor2 = cursor1 + 64;                                  // 3136
    unsigned int* pack1 = (unsigned int*)(cursor2 + NCTR2);       // 49*40960
    unsigned int* pack2 = pack1 + (size_t)NB1 * CAP1;             // 3136*1024
    unsigned short* fbuf1 = (unsigned short*)(pack2 + (size_t)NCTR2 * CAP2);
    unsigned short* h1    = fbuf1 + (size_t)N_NODES * D;          // N*128 bf16
    unsigned int* f8feat  = (unsigned int*)(h1 + (size_t)N_NODES * D);   // N*32
    unsigned int* h1f8    = f8feat + (size_t)N_NODES * (D / 4);          // N*32
    unsigned short* wp1   = (unsigned short*)(h1f8 + (size_t)N_NODES * (D / 4));
    unsigned short* wp2   = wp1 + 256 * 128;
    unsigned short* wpo   = wp2 + 256 * 128;                      // 128*64

    // ---- zero relative cursors (12.8 KB) ----
    hipMemsetAsync(cursor1, 0, (64 + NCTR2) * sizeof(int), stream);

    // ---- prep: bin pass A ∥ cvt (bf16+fp8) ∥ weight pack ----
    prep_k<<<EB1 + CVTB + PKB, 256, 0, stream>>>(src, dst, cursor1, pack1,
                                                 feat, fbuf1, f8feat,
                                                 Wself1, Wneigh1, Wself2, Wneigh2,
                                                 Wout, wp1, wp2, wpo);

    // ---- bin pass B ----
    bin2_k<<<NB1 * SUBB, 256, 0, stream>>>(cursor1, cursor2, pack1, pack2);

    // ---- layer 1 (fused gather+GEMM, fp8 payload; writes h1 + fp8 shadow) ----
    fused_k<false><<<NPART, 256, 0, stream>>>(fbuf1, (const unsigned char*)f8feat,
                                              pack2, cursor2,
                                              (const short8*)wp1, b1, h1,
                                              (unsigned char*)h1f8,
                                              nullptr, nullptr, nullptr);

    // ---- layer 2 + output projection (fp8 payload) ----
    fused_k<true><<<NPART, 256, 0, stream>>>(h1, (const unsigned char*)h1f8,
                                             pack2, cursor2,
                                             (const short8*)wp2, b2, nullptr, nullptr,
                                             (const short8*)wpo, bout, out);
}

// Round 14
// 182.988 us; speedup vs baseline: 1.0419x; 1.0419x over previous
//
#include <hip/hip_runtime.h>
#include <hip/hip_bf16.h>

constexpr int N_NODES = 100000;
constexpr int N_EDGES = 1600000;
constexpr int D = 128;
constexpr int N_CLASSES = 64;

constexpr int PART_NODES = 32;                 // nodes per partition
constexpr int NPART = N_NODES / PART_NODES;    // 3125 (exact)
constexpr int NB1 = 49;                        // coarse buckets (2048 nodes)
constexpr int CAP1 = 40960;                    // entries per coarse bucket
constexpr int SUBB = 10;                       // pass-B sub-blocks per bucket
constexpr int CHUNK = CAP1 / SUBB;             // 4096
constexpr int CAP2 = 1024;                     // per-partition slab (mean 512)
constexpr int NCTR2 = NB1 * 64;                // 3136 fine counters (3125 used)
constexpr int EB1 = (N_EDGES + 1023) / 1024;   // 1563 bin1 blocks
constexpr int CVTB = N_NODES * (D / 4) / 256;  // 12500 cvt blocks (exact)
constexpr int PKB = 36;                        // 144 weight tiles / 4 per block

typedef __attribute__((ext_vector_type(8))) short short8;
typedef __attribute__((ext_vector_type(4))) float f32x4;
typedef __attribute__((ext_vector_type(2))) float f32x2;

static __device__ __forceinline__ float bf2f(unsigned int lo16) {
    unsigned int x = lo16 << 16;
    return __builtin_bit_cast(float, x);
}
static __device__ __forceinline__ unsigned short f2bf(float f) {
    unsigned int x = __builtin_bit_cast(unsigned int, f);
    x += 0x7fffu + ((x >> 16) & 1u);          // RNE
    return (unsigned short)(x >> 16);
}
static __device__ __forceinline__ unsigned int pack4_fp8(float a, float b,
                                                         float c, float d) {
    int v = __builtin_amdgcn_cvt_pk_fp8_f32(a, b, 0, false);   // low word
    v = __builtin_amdgcn_cvt_pk_fp8_f32(c, d, v, true);        // high word
    return (unsigned int)v;
}
static __device__ __forceinline__ unsigned char f2fp8(float a) {
    return (unsigned char)(__builtin_amdgcn_cvt_pk_fp8_f32(a, a, 0, false) & 0xff);
}
// decode 8 fp8 -> 4 packed f32x2 accumulators (4 cvt + 4 v_pk_add_f32)
static __device__ __forceinline__ void dec8v(uint2 u, f32x2* a2) {
    a2[0] += __builtin_amdgcn_cvt_pk_f32_fp8(u.x, false);
    a2[1] += __builtin_amdgcn_cvt_pk_f32_fp8(u.x, true);
    a2[2] += __builtin_amdgcn_cvt_pk_f32_fp8(u.y, false);
    a2[3] += __builtin_amdgcn_cvt_pk_f32_fp8(u.y, true);
}

// ---------------------------------------------------------------------------
// 1) prep: [bin1: LDS sort by coarse bucket, RELATIVE cursors (pre-zeroed by
//    memset)] ∥ [feat fp32->bf16+fp8] ∥ [weight packing]
// ---------------------------------------------------------------------------
__global__ __launch_bounds__(256) void prep_k(const int* __restrict__ src,
                                              const int* __restrict__ dst,
                                              int* __restrict__ cursor1,
                                              unsigned int* __restrict__ pack1,
                                              const float* __restrict__ feat,
                                              unsigned short* __restrict__ fbuf,
                                              unsigned int* __restrict__ f8buf,
                                              const float* __restrict__ Ws1,
                                              const float* __restrict__ Wn1,
                                              const float* __restrict__ Ws2,
                                              const float* __restrict__ Wn2,
                                              const float* __restrict__ Wo,
                                              unsigned short* __restrict__ wp1,
                                              unsigned short* __restrict__ wp2,
                                              unsigned short* __restrict__ wpo) {
    __shared__ unsigned int lpay[1024];
    __shared__ unsigned char lcb[1024];
    __shared__ int hist[NB1], loff[NB1], gpos[NB1], lcur[NB1];

    const int b = blockIdx.x;
    const int t = threadIdx.x;

    if (b < EB1) {
        // ---- bin pass A (relative cursor: pos = cb*CAP1 + rel) ----
        const int ebase = b * 1024;
        int nblk = N_EDGES - ebase;
        if (nblk > 1024) nblk = 1024;
        const bool ok = (t * 4 < nblk);

        if (t < NB1) hist[t] = 0;
        __syncthreads();

        int4 d4, s4;
        if (ok) {
            d4 = *(const int4*)(dst + ebase + t * 4);
            s4 = *(const int4*)(src + ebase + t * 4);
            atomicAdd(&hist[d4.x >> 11], 1);
            atomicAdd(&hist[d4.y >> 11], 1);
            atomicAdd(&hist[d4.z >> 11], 1);
            atomicAdd(&hist[d4.w >> 11], 1);
        }
        __syncthreads();

        if (t == 0) {
            int run = 0;
            #pragma unroll
            for (int k = 0; k < NB1; ++k) { loff[k] = run; run += hist[k]; }
        }
        __syncthreads();
        if (t < NB1) {
            gpos[t] = atomicAdd(cursor1 + t, hist[t]);   // relative base
            lcur[t] = loff[t];
        }
        __syncthreads();

        if (ok) {
            #pragma unroll
            for (int k = 0; k < 4; ++k) {
                int dd = (k == 0) ? d4.x : (k == 1) ? d4.y : (k == 2) ? d4.z : d4.w;
                int ss = (k == 0) ? s4.x : (k == 1) ? s4.y : (k == 2) ? s4.z : s4.w;
                int cb = dd >> 11;
                int pos = atomicAdd(&lcur[cb], 1);
                lpay[pos] = ((unsigned int)(dd & 2047) << 17) | (unsigned int)ss;
                lcb[pos] = (unsigned char)cb;
            }
        }
        __syncthreads();

        for (int i = t; i < nblk; i += 256) {
            int cb = lcb[i];
            int rel = gpos[cb] + (i - loff[cb]);
            if (rel < CAP1) pack1[(size_t)cb * CAP1 + rel] = lpay[i];
        }
    } else if (b < EB1 + CVTB) {
        int i = (b - EB1) * 256 + t;           // float4 chunk id, 3.2M exact
        float4 v = ((const float4*)feat)[i];
        ushort4 r;
        r.x = f2bf(v.x); r.y = f2bf(v.y); r.z = f2bf(v.z); r.w = f2bf(v.w);
        ((ushort4*)fbuf)[i] = r;
        f8buf[i] = pack4_fp8(v.x, v.y, v.z, v.w);
    } else {
        int g = (b - EB1 - CVTB) * 4 + (t >> 6);   // weight tile 0..143
        if (g >= 144) return;
        int lane = t & 63;
        const float *Wa, *Wb;
        unsigned short* wp;
        int DOUT, bb;
        if (g < 64)       { Wa = Ws1; Wb = Wn1; wp = wp1; DOUT = 128; bb = g; }
        else if (g < 128) { Wa = Ws2; Wb = Wn2; wp = wp2; DOUT = 128; bb = g - 64; }
        else              { Wa = Wo;  Wb = nullptr; wp = wpo; DOUT = 64; bb = g - 128; }
        int NCT = DOUT / 16;
        int kstep = bb / NCT;
        int ct = bb % NCT;
        int col = ct * 16 + (lane & 15);
        int kbase = kstep * 32 + (lane >> 4) * 8;
        unsigned short r[8];
        #pragma unroll
        for (int j = 0; j < 8; ++j) {
            int k = kbase + j;
            float w = (k < 128) ? Wa[(size_t)k * DOUT + col]
                                : Wb[(size_t)(k - 128) * DOUT + col];
            r[j] = f2bf(w);
        }
        *(short8*)(wp + ((size_t)((kstep * NCT + ct) * 64 + lane)) * 8) =
            *(const short8*)r;
    }
}

// ---------------------------------------------------------------------------
// 2) pass B: sort each coarse-bucket chunk by partition (pw = pk>>22),
//    bulk-reserve RELATIVE, full-line run writes. payload2 = pk & 0x3fffff.
// ---------------------------------------------------------------------------
__global__ __launch_bounds__(256) void bin2_k(const int* __restrict__ cursor1,
                                              int* __restrict__ cursor2,
                                              const unsigned int* __restrict__ pack1,
                                              unsigned int* __restrict__ pack2) {
    __shared__ unsigned int lpay[CHUNK];       // 16 KB
    __shared__ unsigned int lsort[CHUNK];      // 16 KB
    __shared__ int hist[64], loff[64], gpos[64], lcur[64];

    const int t = threadIdx.x;
    const int cb = blockIdx.x / SUBB;
    const int sb = blockIdx.x % SUBB;

    int cnt = cursor1[cb];                     // relative count
    if (cnt > CAP1) cnt = CAP1;
    const int base = sb * CHUNK;
    int n = cnt - base;
    if (n <= 0) return;
    if (n > CHUNK) n = CHUNK;

    if (t < 64) hist[t] = 0;
    __syncthreads();

    const unsigned int* gsrc = pack1 + (size_t)cb * CAP1 + base;
    for (int i = t; i < n; i += 256) {
        unsigned int pk = gsrc[i];
        lpay[i] = pk;
        atomicAdd(&hist[pk >> 22], 1);
    }
    __syncthreads();

    if (t == 0) {
        int run = 0;
        #pragma unroll
        for (int k = 0; k < 64; ++k) { loff[k] = run; run += hist[k]; }
    }
    __syncthreads();
    if (t < 64) {
        gpos[t] = atomicAdd(cursor2 + cb * 64 + t, hist[t]);   // relative
        lcur[t] = loff[t];
    }
    __syncthreads();

    for (int i = t; i < n; i += 256) {
        unsigned int pk = lpay[i];
        int pos = atomicAdd(&lcur[pk >> 22], 1);
        lsort[pos] = pk;
    }
    __syncthreads();

    for (int i = t; i < n; i += 256) {
        unsigned int pk = lsort[i];
        int pw = pk >> 22;
        int p = cb * 64 + pw;
        int rel = gpos[pw] + (i - loff[pw]);
        if (rel < CAP2) pack2[((size_t)p << 10) + rel] = pk & 0x003fffffu;
    }
}

// ---------------------------------------------------------------------------
// 3) FUSED layer: one block per partition (32 nodes).
//    Stage slab + per-node counting sort; fp8 register gather (2-deep, the
//    measured-best shape) with packed f32x2 accumulation; bf16 mean into LDS;
//    MFMA GEMM. !OUTPROJ: epilogue writes bf16 h AND its fp8 shadow.
//    OUTPROJ: restage h in LDS, phase C MFMA out = h @ Wout + bout (fp32).
// ---------------------------------------------------------------------------
template <bool OUTPROJ>
__global__ __launch_bounds__(256) void fused_k(const unsigned short* __restrict__ xin,
                                               const unsigned char* __restrict__ x8,
                                               const unsigned int* __restrict__ pack,
                                               const int* __restrict__ cursor2,
                                               const short8* __restrict__ wp,
                                               const float* __restrict__ bias,
                                               unsigned short* __restrict__ xout,
                                               unsigned char* __restrict__ x8out,
                                               const short8* __restrict__ wpo,
                                               const float* __restrict__ bout,
                                               float* __restrict__ outp) {
    __shared__ unsigned int eraw[CAP2];
    __shared__ unsigned int ssrc[CAP2];
    __shared__ int nsh;
    __shared__ int bcnt[32];
    __shared__ int boff[33];
    __shared__ unsigned short mlds[PART_NODES][136];   // stride 272 B

    const int t = threadIdx.x;
    const int p = blockIdx.x;

    if (t == 0) {
        int c = cursor2[p];                    // relative count
        nsh = (c < CAP2) ? c : CAP2;
    }
    if (t < 32) bcnt[t] = 0;
    __syncthreads();
    const int n = nsh;

    // stage slab + per-node histogram
    const unsigned int* gsrc = pack + ((size_t)p << 10);
    for (int i = t; i < n; i += 256) {
        unsigned int pk = gsrc[i];
        eraw[i] = pk;
        atomicAdd(&bcnt[pk >> 17], 1);
    }
    __syncthreads();

    if (t == 0) {
        int s = 0;
        #pragma unroll
        for (int i = 0; i < 32; ++i) { boff[i] = s; s += bcnt[i]; }
        boff[32] = s;
    }
    __syncthreads();
    if (t < 32) bcnt[t] = boff[t];             // reuse as cursor
    __syncthreads();

    for (int i = t; i < n; i += 256) {
        unsigned int pk = eraw[i];
        int pos = atomicAdd(&bcnt[pk >> 17], 1);
        ssrc[pos] = pk & 0x1ffffu;
    }
    __syncthreads();

    // ---- phase A: fp8 gather into mlds (2-deep, packed f32x2 accum) ----
    const int w = t >> 6, lane = t & 63;
    const int sub = lane >> 4;                 // edge slot 0..3
    const int cl = lane & 15;                  // column group (cols cl*8..+7)

    for (int g = 0; g < 8; ++g) {
        const int ni = w * 8 + g;
        const int b = boff[ni];
        const int eN = boff[ni + 1];

        f32x2 a2[4];
        #pragma unroll
        for (int r = 0; r < 4; ++r) a2[r] = {0.f, 0.f};

        int i = b + sub;
        for (; i + 4 < eN; i += 8) {
            int s0 = ssrc[i];
            int s1 = ssrc[i + 4];
            uint2 u0 = *(const uint2*)(x8 + (size_t)s0 * 128 + cl * 8);
            uint2 u1 = *(const uint2*)(x8 + (size_t)s1 * 128 + cl * 8);
            dec8v(u0, a2);
            dec8v(u1, a2);
        }
        if (i < eN) {
            int s0 = ssrc[i];
            uint2 u0 = *(const uint2*)(x8 + (size_t)s0 * 128 + cl * 8);
            dec8v(u0, a2);
        }
        #pragma unroll
        for (int r = 0; r < 4; ++r) {
            float a = a2[r][0], bb = a2[r][1];
            a += __shfl_xor(a, 16);  a += __shfl_xor(a, 32);
            bb += __shfl_xor(bb, 16); bb += __shfl_xor(bb, 32);
            a2[r][0] = a; a2[r][1] = bb;
        }
        float inv = 1.0f / fmaxf((float)(eN - b), 1.0f);
        // lane writes the pair for its sub slot: acc2[sub] (ternary tree, no
        // runtime array index -> stays in registers)
        f32x2 sel = (sub & 2) ? ((sub & 1) ? a2[3] : a2[2])
                              : ((sub & 1) ? a2[1] : a2[0]);
        unsigned int o = ((unsigned int)f2bf(sel[1] * inv) << 16)
                       | (unsigned int)f2bf(sel[0] * inv);
        *(unsigned int*)(&mlds[ni][cl * 8 + sub * 2]) = o;
    }
    __syncthreads();

    // ---- phase B: 32-row GEMM, K=256 (self 0..127 global bf16, mean LDS) ----
    const int frag = w & 1;                    // 16-row fragment 0/1
    const int cg0 = (w >> 1) * 4;              // col-tile group base (of 8)
    const int r15 = lane & 15;
    const int khi = lane >> 4;                 // 0..3
    const int row0 = p * PART_NODES + frag * 16;
    const unsigned short* arow = xin + (size_t)(row0 + r15) * 128 + khi * 8;

    f32x4 acc[4];
    #pragma unroll
    for (int c = 0; c < 4; ++c) acc[c] = {0.f, 0.f, 0.f, 0.f};

    #pragma unroll
    for (int ks = 0; ks < 8; ++ks) {
        short8 a;
        if (ks < 4) a = *(const short8*)(arow + ks * 32);
        else        a = *(const short8*)(&mlds[frag * 16 + r15][(ks - 4) * 32 + khi * 8]);
        #pragma unroll
        for (int c = 0; c < 4; ++c) {
            short8 b = wp[(ks * 8 + cg0 + c) * 64 + lane];
            acc[c] = __builtin_amdgcn_mfma_f32_16x16x32_bf16(a, b, acc[c], 0, 0, 0);
        }
    }

    const int rhi = khi, col0 = r15;
    if (!OUTPROJ) {
        #pragma unroll
        for (int c = 0; c < 4; ++c) {
            float bv = bias[(cg0 + c) * 16 + col0];
            #pragma unroll
            for (int j = 0; j < 4; ++j) {
                float v = fmaxf(acc[c][j] + bv, 0.f);
                size_t off = (size_t)(row0 + rhi * 4 + j) * 128 + (cg0 + c) * 16 + col0;
                xout[off] = f2bf(v);
                x8out[off] = f2fp8(v);         // fp8 shadow for next layer
            }
        }
    } else {
        __syncthreads();                        // all mlds reads done
        // restage h tile (bias+relu) into mlds as bf16
        #pragma unroll
        for (int c = 0; c < 4; ++c) {
            float bv = bias[(cg0 + c) * 16 + col0];
            #pragma unroll
            for (int j = 0; j < 4; ++j) {
                float v = fmaxf(acc[c][j] + bv, 0.f);
                mlds[frag * 16 + rhi * 4 + j][(cg0 + c) * 16 + col0] = f2bf(v);
            }
        }
        __syncthreads();
        // ---- phase C: out[32 x 64] = h[32 x 128] @ Wout + bout ----
        const int frag2 = w & 1;
        const int ct0 = (w >> 1) * 2;          // 2 col-tiles of 4
        f32x4 oacc[2];
        oacc[0] = {0.f, 0.f, 0.f, 0.f};
        oacc[1] = {0.f, 0.f, 0.f, 0.f};
        #pragma unroll
        for (int ks = 0; ks < 4; ++ks) {
            short8 a = *(const short8*)(&mlds[frag2 * 16 + r15][ks * 32 + khi * 8]);
            #pragma unroll
            for (int c = 0; c < 2; ++c) {
                short8 b = wpo[(ks * 4 + ct0 + c) * 64 + lane];
                oacc[c] = __builtin_amdgcn_mfma_f32_16x16x32_bf16(a, b, oacc[c], 0, 0, 0);
            }
        }
        #pragma unroll
        for (int c = 0; c < 2; ++c) {
            float bv = bout[(ct0 + c) * 16 + col0];
            #pragma unroll
            for (int j = 0; j < 4; ++j) {
                outp[(size_t)(p * PART_NODES + frag2 * 16 + rhi * 4 + j) * N_CLASSES
                     + (ct0 + c) * 16 + col0] = oacc[c][j] + bv;
            }
        }
    }
}

// ---------------------------------------------------------------------------
extern "C" void kernel_launch(void* const* d_in, const int* in_sizes, int n_in,
                              void* d_out, int out_size, void* d_ws, size_t ws_size,
                              hipStream_t stream) {
    const float* feat   = (const float*)d_in[0];
    const int*   src    = (const int*)d_in[1];
    const int*   dst    = (const int*)d_in[2];
    const float* Wself1 = (const float*)d_in[3];
    const float* Wneigh1= (const float*)d_in[4];
    const float* b1     = (const float*)d_in[5];
    const float* Wself2 = (const float*)d_in[6];
    const float* Wneigh2= (const float*)d_in[7];
    const float* b2     = (const float*)d_in[8];
    const float* Wout   = (const float*)d_in[9];
    const float* bout   = (const float*)d_in[10];
    float* out = (float*)d_out;
    (void)ws_size;

    // workspace layout (~100 MB)
    int* cursor1 = (int*)d_ws;                                    // 49 (pad 64)
    int* cursor2 = cursor1 + 64;                                  // 3136
    unsigned int* pack1 = (unsigned int*)(cursor2 + NCTR2);       // 49*40960
    unsigned int* pack2 = pack1 + (size_t)NB1 * CAP1;             // 3136*1024
    unsigned short* fbuf1 = (unsigned short*)(pack2 + (size_t)NCTR2 * CAP2);
    unsigned short* h1    = fbuf1 + (size_t)N_NODES * D;          // N*128 bf16
    unsigned int* f8feat  = (unsigned int*)(h1 + (size_t)N_NODES * D);   // N*32
    unsigned int* h1f8    = f8feat + (size_t)N_NODES * (D / 4);          // N*32
    unsigned short* wp1   = (unsigned short*)(h1f8 + (size_t)N_NODES * (D / 4));
    unsigned short* wp2   = wp1 + 256 * 128;
    unsigned short* wpo   = wp2 + 256 * 128;                      // 128*64

    // ---- zero relative cursors (12.8 KB) ----
    hipMemsetAsync(cursor1, 0, (64 + NCTR2) * sizeof(int), stream);

    // ---- prep: bin pass A ∥ cvt (bf16+fp8) ∥ weight pack ----
    prep_k<<<EB1 + CVTB + PKB, 256, 0, stream>>>(src, dst, cursor1, pack1,
                                                 feat, fbuf1, f8feat,
                                                 Wself1, Wneigh1, Wself2, Wneigh2,
                                                 Wout, wp1, wp2, wpo);

    // ---- bin pass B ----
    bin2_k<<<NB1 * SUBB, 256, 0, stream>>>(cursor1, cursor2, pack1, pack2);

    // ---- layer 1 (fused gather+GEMM, fp8 payload; writes h1 + fp8 shadow) ----
    fused_k<false><<<NPART, 256, 0, stream>>>(fbuf1, (const unsigned char*)f8feat,
                                              pack2, cursor2,
                                              (const short8*)wp1, b1, h1,
                                              (unsigned char*)h1f8,
                                              nullptr, nullptr, nullptr);

    // ---- layer 2 + output projection (fp8 payload) ----
    fused_k<true><<<NPART, 256, 0, stream>>>(h1, (const unsigned char*)h1f8,
                                             pack2, cursor2,
                                             (const short8*)wp2, b2, nullptr, nullptr,
                                             (const short8*)wpo, bout, out);
}

// Round 15
// 164.340 us; speedup vs baseline: 1.1601x; 1.1135x over previous
//
#include <hip/hip_runtime.h>
#include <hip/hip_bf16.h>

constexpr int N_NODES = 100000;
constexpr int N_EDGES = 1600000;
constexpr int D = 128;
constexpr int N_CLASSES = 64;

constexpr int PART_NODES = 32;                 // nodes per partition
constexpr int NPART = N_NODES / PART_NODES;    // 3125 (exact)
constexpr int NB1 = 49;                        // coarse buckets (2048 nodes)
constexpr int CAP1 = 40960;                    // entries per coarse bucket
constexpr int SUBB = 10;                       // pass-B sub-blocks per bucket
constexpr int CHUNK = CAP1 / SUBB;             // 4096
constexpr int CAP2 = 1024;                     // per-partition slab (mean 512)
constexpr int NCTR2 = NB1 * 64;                // 3136 fine counters (3125 used)
constexpr int BE = 2048;                       // edges per bin1 block
constexpr int EB1 = (N_EDGES + BE - 1) / BE;   // 782 bin1 blocks
constexpr int CVTB = N_NODES * (D / 4) / 256;  // 12500 cvt blocks (exact)
constexpr int PKB = 36;                        // 144 weight tiles / 4 per block

typedef __attribute__((ext_vector_type(8))) short short8;
typedef __attribute__((ext_vector_type(4))) float f32x4;
typedef __attribute__((ext_vector_type(2))) float f32x2;

static __device__ __forceinline__ float bf2f(unsigned int lo16) {
    unsigned int x = lo16 << 16;
    return __builtin_bit_cast(float, x);
}
static __device__ __forceinline__ unsigned short f2bf(float f) {
    unsigned int x = __builtin_bit_cast(unsigned int, f);
    x += 0x7fffu + ((x >> 16) & 1u);          // RNE
    return (unsigned short)(x >> 16);
}
static __device__ __forceinline__ unsigned int pack4_fp8(float a, float b,
                                                         float c, float d) {
    int v = __builtin_amdgcn_cvt_pk_fp8_f32(a, b, 0, false);   // low word
    v = __builtin_amdgcn_cvt_pk_fp8_f32(c, d, v, true);        // high word
    return (unsigned int)v;
}
static __device__ __forceinline__ unsigned char f2fp8(float a) {
    return (unsigned char)(__builtin_amdgcn_cvt_pk_fp8_f32(a, a, 0, false) & 0xff);
}
// round-12 proven decode: 4 cvt + 8 scalar adds (VGPR-lean, measured best)
static __device__ __forceinline__ void dec8(uint2 u, float* acc) {
    f32x2 q;
    q = __builtin_amdgcn_cvt_pk_f32_fp8(u.x, false); acc[0] += q[0]; acc[1] += q[1];
    q = __builtin_amdgcn_cvt_pk_f32_fp8(u.x, true);  acc[2] += q[0]; acc[3] += q[1];
    q = __builtin_amdgcn_cvt_pk_f32_fp8(u.y, false); acc[4] += q[0]; acc[5] += q[1];
    q = __builtin_amdgcn_cvt_pk_f32_fp8(u.y, true);  acc[6] += q[0]; acc[7] += q[1];
}

// ---------------------------------------------------------------------------
// 1) prep: [bin1: LDS sort by coarse bucket, 2048 edges/block, RELATIVE
//    cursors (pre-zeroed)] ∥ [feat fp32->bf16+fp8] ∥ [weight packing]
// ---------------------------------------------------------------------------
__global__ __launch_bounds__(256) void prep_k(const int* __restrict__ src,
                                              const int* __restrict__ dst,
                                              int* __restrict__ cursor1,
                                              unsigned int* __restrict__ pack1,
                                              const float* __restrict__ feat,
                                              unsigned short* __restrict__ fbuf,
                                              unsigned int* __restrict__ f8buf,
                                              const float* __restrict__ Ws1,
                                              const float* __restrict__ Wn1,
                                              const float* __restrict__ Ws2,
                                              const float* __restrict__ Wn2,
                                              const float* __restrict__ Wo,
                                              unsigned short* __restrict__ wp1,
                                              unsigned short* __restrict__ wp2,
                                              unsigned short* __restrict__ wpo) {
    __shared__ unsigned int lpay[BE];
    __shared__ unsigned char lcb[BE];
    __shared__ int hist[NB1], loff[NB1], gpos[NB1], lcur[NB1];

    const int b = blockIdx.x;
    const int t = threadIdx.x;

    if (b < EB1) {
        // ---- bin pass A: 2048 edges, 8 per thread ----
        const int ebase = b * BE;
        int nblk = N_EDGES - ebase;
        if (nblk > BE) nblk = BE;              // always a multiple of 512
        const bool ok = (t * 8 < nblk);

        if (t < NB1) hist[t] = 0;
        __syncthreads();

        int4 d4a, s4a, d4b, s4b;
        if (ok) {
            d4a = *(const int4*)(dst + ebase + t * 8);
            d4b = *(const int4*)(dst + ebase + t * 8 + 4);
            s4a = *(const int4*)(src + ebase + t * 8);
            s4b = *(const int4*)(src + ebase + t * 8 + 4);
            atomicAdd(&hist[d4a.x >> 11], 1);
            atomicAdd(&hist[d4a.y >> 11], 1);
            atomicAdd(&hist[d4a.z >> 11], 1);
            atomicAdd(&hist[d4a.w >> 11], 1);
            atomicAdd(&hist[d4b.x >> 11], 1);
            atomicAdd(&hist[d4b.y >> 11], 1);
            atomicAdd(&hist[d4b.z >> 11], 1);
            atomicAdd(&hist[d4b.w >> 11], 1);
        }
        __syncthreads();

        if (t == 0) {
            int run = 0;
            #pragma unroll
            for (int k = 0; k < NB1; ++k) { loff[k] = run; run += hist[k]; }
        }
        __syncthreads();
        if (t < NB1) {
            gpos[t] = atomicAdd(cursor1 + t, hist[t]);   // relative base
            lcur[t] = loff[t];
        }
        __syncthreads();

        if (ok) {
            #pragma unroll
            for (int k = 0; k < 8; ++k) {
                int dd, ss;
                if (k < 4) {
                    dd = (k == 0) ? d4a.x : (k == 1) ? d4a.y : (k == 2) ? d4a.z : d4a.w;
                    ss = (k == 0) ? s4a.x : (k == 1) ? s4a.y : (k == 2) ? s4a.z : s4a.w;
                } else {
                    dd = (k == 4) ? d4b.x : (k == 5) ? d4b.y : (k == 6) ? d4b.z : d4b.w;
                    ss = (k == 4) ? s4b.x : (k == 5) ? s4b.y : (k == 6) ? s4b.z : s4b.w;
                }
                int cb = dd >> 11;
                int pos = atomicAdd(&lcur[cb], 1);
                lpay[pos] = ((unsigned int)(dd & 2047) << 17) | (unsigned int)ss;
                lcb[pos] = (unsigned char)cb;
            }
        }
        __syncthreads();

        for (int i = t; i < nblk; i += 256) {
            int cb = lcb[i];
            int rel = gpos[cb] + (i - loff[cb]);
            if (rel < CAP1) pack1[(size_t)cb * CAP1 + rel] = lpay[i];
        }
    } else if (b < EB1 + CVTB) {
        int i = (b - EB1) * 256 + t;           // float4 chunk id, 3.2M exact
        float4 v = ((const float4*)feat)[i];
        ushort4 r;
        r.x = f2bf(v.x); r.y = f2bf(v.y); r.z = f2bf(v.z); r.w = f2bf(v.w);
        ((ushort4*)fbuf)[i] = r;
        f8buf[i] = pack4_fp8(v.x, v.y, v.z, v.w);
    } else {
        int g = (b - EB1 - CVTB) * 4 + (t >> 6);   // weight tile 0..143
        if (g >= 144) return;
        int lane = t & 63;
        const float *Wa, *Wb;
        unsigned short* wp;
        int DOUT, bb;
        if (g < 64)       { Wa = Ws1; Wb = Wn1; wp = wp1; DOUT = 128; bb = g; }
        else if (g < 128) { Wa = Ws2; Wb = Wn2; wp = wp2; DOUT = 128; bb = g - 64; }
        else              { Wa = Wo;  Wb = nullptr; wp = wpo; DOUT = 64; bb = g - 128; }
        int NCT = DOUT / 16;
        int kstep = bb / NCT;
        int ct = bb % NCT;
        int col = ct * 16 + (lane & 15);
        int kbase = kstep * 32 + (lane >> 4) * 8;
        unsigned short r[8];
        #pragma unroll
        for (int j = 0; j < 8; ++j) {
            int k = kbase + j;
            float w = (k < 128) ? Wa[(size_t)k * DOUT + col]
                                : Wb[(size_t)(k - 128) * DOUT + col];
            r[j] = f2bf(w);
        }
        *(short8*)(wp + ((size_t)((kstep * NCT + ct) * 64 + lane)) * 8) =
            *(const short8*)r;
    }
}

// ---------------------------------------------------------------------------
// 2) pass B: sort each coarse-bucket chunk by partition (pw = pk>>22),
//    bulk-reserve RELATIVE, full-line run writes. payload2 = pk & 0x3fffff.
// ---------------------------------------------------------------------------
__global__ __launch_bounds__(256) void bin2_k(const int* __restrict__ cursor1,
                                              int* __restrict__ cursor2,
                                              const unsigned int* __restrict__ pack1,
                                              unsigned int* __restrict__ pack2) {
    __shared__ unsigned int lpay[CHUNK];       // 16 KB
    __shared__ unsigned int lsort[CHUNK];      // 16 KB
    __shared__ int hist[64], loff[64], gpos[64], lcur[64];

    const int t = threadIdx.x;
    const int cb = blockIdx.x / SUBB;
    const int sb = blockIdx.x % SUBB;

    int cnt = cursor1[cb];                     // relative count
    if (cnt > CAP1) cnt = CAP1;
    const int base = sb * CHUNK;
    int n = cnt - base;
    if (n <= 0) return;
    if (n > CHUNK) n = CHUNK;

    if (t < 64) hist[t] = 0;
    __syncthreads();

    const unsigned int* gsrc = pack1 + (size_t)cb * CAP1 + base;
    for (int i = t; i < n; i += 256) {
        unsigned int pk = gsrc[i];
        lpay[i] = pk;
        atomicAdd(&hist[pk >> 22], 1);
    }
    __syncthreads();

    if (t == 0) {
        int run = 0;
        #pragma unroll
        for (int k = 0; k < 64; ++k) { loff[k] = run; run += hist[k]; }
    }
    __syncthreads();
    if (t < 64) {
        gpos[t] = atomicAdd(cursor2 + cb * 64 + t, hist[t]);   // relative
        lcur[t] = loff[t];
    }
    __syncthreads();

    for (int i = t; i < n; i += 256) {
        unsigned int pk = lpay[i];
        int pos = atomicAdd(&lcur[pk >> 22], 1);
        lsort[pos] = pk;
    }
    __syncthreads();

    for (int i = t; i < n; i += 256) {
        unsigned int pk = lsort[i];
        int pw = pk >> 22;
        int p = cb * 64 + pw;
        int rel = gpos[pw] + (i - loff[pw]);
        if (rel < CAP2) pack2[((size_t)p << 10) + rel] = pk & 0x003fffffu;
    }
}

// ---------------------------------------------------------------------------
// 3) FUSED layer (round-12 proven shape, VGPR 36): one block per partition.
//    Stage slab + per-node counting sort; fp8 register gather 2-deep;
//    bf16 mean into LDS; MFMA GEMM.
//    !OUTPROJ: epilogue writes bf16 h AND its fp8 shadow.
//    OUTPROJ: restage h in LDS, phase C MFMA out = h @ Wout + bout (fp32).
// ---------------------------------------------------------------------------
template <bool OUTPROJ>
__global__ __launch_bounds__(256) void fused_k(const unsigned short* __restrict__ xin,
                                               const unsigned char* __restrict__ x8,
                                               const unsigned int* __restrict__ pack,
                                               const int* __restrict__ cursor2,
                                               const short8* __restrict__ wp,
                                               const float* __restrict__ bias,
                                               unsigned short* __restrict__ xout,
                                               unsigned char* __restrict__ x8out,
                                               const short8* __restrict__ wpo,
                                               const float* __restrict__ bout,
                                               float* __restrict__ outp) {
    __shared__ unsigned int eraw[CAP2];
    __shared__ unsigned int ssrc[CAP2];
    __shared__ int nsh;
    __shared__ int bcnt[32];
    __shared__ int boff[33];
    __shared__ unsigned short mlds[PART_NODES][136];   // stride 272 B

    const int t = threadIdx.x;
    const int p = blockIdx.x;

    if (t == 0) {
        int c = cursor2[p];                    // relative count
        nsh = (c < CAP2) ? c : CAP2;
    }
    if (t < 32) bcnt[t] = 0;
    __syncthreads();
    const int n = nsh;

    // stage slab + per-node histogram
    const unsigned int* gsrc = pack + ((size_t)p << 10);
    for (int i = t; i < n; i += 256) {
        unsigned int pk = gsrc[i];
        eraw[i] = pk;
        atomicAdd(&bcnt[pk >> 17], 1);
    }
    __syncthreads();

    if (t == 0) {
        int s = 0;
        #pragma unroll
        for (int i = 0; i < 32; ++i) { boff[i] = s; s += bcnt[i]; }
        boff[32] = s;
    }
    __syncthreads();
    if (t < 32) bcnt[t] = boff[t];             // reuse as cursor
    __syncthreads();

    for (int i = t; i < n; i += 256) {
        unsigned int pk = eraw[i];
        int pos = atomicAdd(&bcnt[pk >> 17], 1);
        ssrc[pos] = pk & 0x1ffffu;
    }
    __syncthreads();

    // ---- phase A: fp8 gather into mlds (2-deep, scalar acc — measured best) ----
    const int w = t >> 6, lane = t & 63;
    const int sub = lane >> 4;                 // edge slot 0..3
    const int cl = lane & 15;                  // column group (cols cl*8..+7)

    for (int g = 0; g < 8; ++g) {
        const int ni = w * 8 + g;
        const int b = boff[ni];
        const int eN = boff[ni + 1];

        float acc[8];
        #pragma unroll
        for (int r = 0; r < 8; ++r) acc[r] = 0.f;

        int i = b + sub;
        for (; i + 4 < eN; i += 8) {
            int s0 = ssrc[i];
            int s1 = ssrc[i + 4];
            uint2 u0 = *(const uint2*)(x8 + (size_t)s0 * 128 + cl * 8);
            uint2 u1 = *(const uint2*)(x8 + (size_t)s1 * 128 + cl * 8);
            dec8(u0, acc);
            dec8(u1, acc);
        }
        if (i < eN) {
            int s0 = ssrc[i];
            uint2 u0 = *(const uint2*)(x8 + (size_t)s0 * 128 + cl * 8);
            dec8(u0, acc);
        }
        #pragma unroll
        for (int r = 0; r < 8; ++r) {
            acc[r] += __shfl_xor(acc[r], 16);
            acc[r] += __shfl_xor(acc[r], 32);
        }
        float inv = 1.0f / fmaxf((float)(eN - b), 1.0f);
        float lo = acc[sub * 2 + 0] * inv;
        float hi = acc[sub * 2 + 1] * inv;
        unsigned int o = ((unsigned int)f2bf(hi) << 16) | (unsigned int)f2bf(lo);
        *(unsigned int*)(&mlds[ni][cl * 8 + sub * 2]) = o;
    }
    __syncthreads();

    // ---- phase B: 32-row GEMM, K=256 (self 0..127 global bf16, mean LDS) ----
    const int frag = w & 1;                    // 16-row fragment 0/1
    const int cg0 = (w >> 1) * 4;              // col-tile group base (of 8)
    const int r15 = lane & 15;
    const int khi = lane >> 4;                 // 0..3
    const int row0 = p * PART_NODES + frag * 16;
    const unsigned short* arow = xin + (size_t)(row0 + r15) * 128 + khi * 8;

    f32x4 acc[4];
    #pragma unroll
    for (int c = 0; c < 4; ++c) acc[c] = {0.f, 0.f, 0.f, 0.f};

    #pragma unroll
    for (int ks = 0; ks < 8; ++ks) {
        short8 a;
        if (ks < 4) a = *(const short8*)(arow + ks * 32);
        else        a = *(const short8*)(&mlds[frag * 16 + r15][(ks - 4) * 32 + khi * 8]);
        #pragma unroll
        for (int c = 0; c < 4; ++c) {
            short8 b = wp[(ks * 8 + cg0 + c) * 64 + lane];
            acc[c] = __builtin_amdgcn_mfma_f32_16x16x32_bf16(a, b, acc[c], 0, 0, 0);
        }
    }

    const int rhi = khi, col0 = r15;
    if (!OUTPROJ) {
        #pragma unroll
        for (int c = 0; c < 4; ++c) {
            float bv = bias[(cg0 + c) * 16 + col0];
            #pragma unroll
            for (int j = 0; j < 4; ++j) {
                float v = fmaxf(acc[c][j] + bv, 0.f);
                size_t off = (size_t)(row0 + rhi * 4 + j) * 128 + (cg0 + c) * 16 + col0;
                xout[off] = f2bf(v);
                x8out[off] = f2fp8(v);         // fp8 shadow for next layer
            }
        }
    } else {
        __syncthreads();                        // all mlds reads done
        // restage h tile (bias+relu) into mlds as bf16
        #pragma unroll
        for (int c = 0; c < 4; ++c) {
            float bv = bias[(cg0 + c) * 16 + col0];
            #pragma unroll
            for (int j = 0; j < 4; ++j) {
                float v = fmaxf(acc[c][j] + bv, 0.f);
                mlds[frag * 16 + rhi * 4 + j][(cg0 + c) * 16 + col0] = f2bf(v);
            }
        }
        __syncthreads();
        // ---- phase C: out[32 x 64] = h[32 x 128] @ Wout + bout ----
        const int frag2 = w & 1;
        const int ct0 = (w >> 1) * 2;          // 2 col-tiles of 4
        f32x4 oacc[2];
        oacc[0] = {0.f, 0.f, 0.f, 0.f};
        oacc[1] = {0.f, 0.f, 0.f, 0.f};
        #pragma unroll
        for (int ks = 0; ks < 4; ++ks) {
            short8 a = *(const short8*)(&mlds[frag2 * 16 + r15][ks * 32 + khi * 8]);
            #pragma unroll
            for (int c = 0; c < 2; ++c) {
                short8 b = wpo[(ks * 4 + ct0 + c) * 64 + lane];
                oacc[c] = __builtin_amdgcn_mfma_f32_16x16x32_bf16(a, b, oacc[c], 0, 0, 0);
            }
        }
        #pragma unroll
        for (int c = 0; c < 2; ++c) {
            float bv = bout[(ct0 + c) * 16 + col0];
            #pragma unroll
            for (int j = 0; j < 4; ++j) {
                outp[(size_t)(p * PART_NODES + frag2 * 16 + rhi * 4 + j) * N_CLASSES
                     + (ct0 + c) * 16 + col0] = oacc[c][j] + bv;
            }
        }
    }
}

// ---------------------------------------------------------------------------
extern "C" void kernel_launch(void* const* d_in, const int* in_sizes, int n_in,
                              void* d_out, int out_size, void* d_ws, size_t ws_size,
                              hipStream_t stream) {
    const float* feat   = (const float*)d_in[0];
    const int*   src    = (const int*)d_in[1];
    const int*   dst    = (const int*)d_in[2];
    const float* Wself1 = (const float*)d_in[3];
    const float* Wneigh1= (const float*)d_in[4];
    const float* b1     = (const float*)d_in[5];
    const float* Wself2 = (const float*)d_in[6];
    const float* Wneigh2= (const float*)d_in[7];
    const float* b2     = (const float*)d_in[8];
    const float* Wout   = (const float*)d_in[9];
    const float* bout   = (const float*)d_in[10];
    float* out = (float*)d_out;
    (void)ws_size;

    // workspace layout (~100 MB)
    int* cursor1 = (int*)d_ws;                                    // 49 (pad 64)
    int* cursor2 = cursor1 + 64;                                  // 3136
    unsigned int* pack1 = (unsigned int*)(cursor2 + NCTR2);       // 49*40960
    unsigned int* pack2 = pack1 + (size_t)NB1 * CAP1;             // 3136*1024
    unsigned short* fbuf1 = (unsigned short*)(pack2 + (size_t)NCTR2 * CAP2);
    unsigned short* h1    = fbuf1 + (size_t)N_NODES * D;          // N*128 bf16
    unsigned int* f8feat  = (unsigned int*)(h1 + (size_t)N_NODES * D);   // N*32
    unsigned int* h1f8    = f8feat + (size_t)N_NODES * (D / 4);          // N*32
    unsigned short* wp1   = (unsigned short*)(h1f8 + (size_t)N_NODES * (D / 4));
    unsigned short* wp2   = wp1 + 256 * 128;
    unsigned short* wpo   = wp2 + 256 * 128;                      // 128*64

    // ---- zero relative cursors (12.8 KB) ----
    hipMemsetAsync(cursor1, 0, (64 + NCTR2) * sizeof(int), stream);

    // ---- prep: bin pass A ∥ cvt (bf16+fp8) ∥ weight pack ----
    prep_k<<<EB1 + CVTB + PKB, 256, 0, stream>>>(src, dst, cursor1, pack1,
                                                 feat, fbuf1, f8feat,
                                                 Wself1, Wneigh1, Wself2, Wneigh2,
                                                 Wout, wp1, wp2, wpo);

    // ---- bin pass B ----
    bin2_k<<<NB1 * SUBB, 256, 0, stream>>>(cursor1, cursor2, pack1, pack2);

    // ---- layer 1 (fused gather+GEMM, fp8 payload; writes h1 + fp8 shadow) ----
    fused_k<false><<<NPART, 256, 0, stream>>>(fbuf1, (const unsigned char*)f8feat,
                                              pack2, cursor2,
                                              (const short8*)wp1, b1, h1,
                                              (unsigned char*)h1f8,
                                              nullptr, nullptr, nullptr);

    // ---- layer 2 + output projection (fp8 payload) ----
    fused_k<true><<<NPART, 256, 0, stream>>>(h1, (const unsigned char*)h1f8,
                                             pack2, cursor2,
                                             (const short8*)wp2, b2, nullptr, nullptr,
                                             (const short8*)wpo, bout, out);
}